// Round 4
// baseline (613.125 us; speedup 1.0000x reference)
//
#include <hip/hip_runtime.h>

// N=64, CIN=COUT=64, T=256, V=25, S=3, REL=8
// ws layout (bytes):
//   [0, 8192)                : BN stats: sum at [o*16], sumsq at [1024 + o*16] (fp32)
//                              (overlaps xm region; memset AFTER k_small has consumed xm)
//   [0, 409600)              : xm[n][c][v] fp32 (102400 floats) -- k_xm -> k_small only
//   [409600, +17203200)      : R_bf16[s][n][o][u25][v28]  (v pad 25..27 = 0)

#define WS_R_BYTE   409600

typedef __attribute__((ext_vector_type(8))) short bf16x8;
typedef __attribute__((ext_vector_type(4))) float f32x4;
typedef __attribute__((ext_vector_type(2))) unsigned int u32x2;
typedef __attribute__((ext_vector_type(4))) unsigned int u32x4;

static __device__ __forceinline__ unsigned short f2bf(float f) {
    unsigned int u = __float_as_uint(f);
    u += 0x7fff + ((u >> 16) & 1);          // RNE (finite values) -- harness-verified
    return (unsigned short)(u >> 16);
}
static __device__ __forceinline__ unsigned pk2(float lo, float hi) {
    return (unsigned)f2bf(lo) | ((unsigned)f2bf(hi) << 16);
}

union BFRU { bf16x8 v; unsigned u[4]; u32x2 d[2]; };

// ---------------- K1: xm = mean over T (coalesced rewrite) ----------------
// block = (n, c): 4096 blocks x 256 thr; float4 loads -> LDS -> column reduce
__global__ __launch_bounds__(256) void k_xm(const float* __restrict__ x,
                                            float* __restrict__ ws) {
    __shared__ float sm[6400];
    __shared__ float part[200];
    const int tid = threadIdx.x;
    const int n = blockIdx.x >> 6, c = blockIdx.x & 63;
    const float4* p = (const float4*)(x + (unsigned)(n * 64 + c) * 6400u);
    float4* s4 = (float4*)sm;
    for (int i = tid; i < 1600; i += 256) s4[i] = p[i];
    __syncthreads();
    if (tid < 200) {
        int v = tid % 25, g = tid / 25;    // g = t-chunk 0..7
        float s = 0.f;
        for (int tt = 0; tt < 32; tt++) s += sm[(g * 32 + tt) * 25 + v];
        part[tid] = s;
    }
    __syncthreads();
    if (tid < 25) {
        float s = 0.f;
        #pragma unroll
        for (int g = 0; g < 8; g++) s += part[g * 25 + tid];
        ws[n * 1600 + c * 25 + tid] = s * (1.f / 256.f);
    }
}

// ---------------- K2: build R_bf16[s][n][o][u25][v28] ----------------
// one block per (s,n); 512 threads; 60000 B LDS
__global__ __launch_bounds__(512) void k_small(
    const float* __restrict__ ws, unsigned short* __restrict__ Rg,
    const float* __restrict__ A, const float* __restrict__ alphap,
    const float* __restrict__ w1, const float* __restrict__ b1,
    const float* __restrict__ w2, const float* __restrict__ b2,
    const float* __restrict__ w4, const float* __restrict__ b4,
    const float* __restrict__ pw1, const float* __restrict__ pb1,
    const float* __restrict__ pw2, const float* __restrict__ pb2,
    const float* __restrict__ dww, const float* __restrict__ pjw,
    const float* __restrict__ beta, const float* __restrict__ gamma) {
    __shared__ float sm[15000];
    const int tid = threadIdx.x;
    const int s = blockIdx.x >> 6;   // 0..2
    const int n = blockIdx.x & 63;   // 0..63
    const float alpha = alphap[0];
    const float gam = gamma[s], bet = beta[s];

    for (int i = tid; i < 1600; i += 512) sm[5000 + i] = ws[n * 1600 + i];
    __syncthreads();

    for (int i = tid; i < 400; i += 512) {
        int half = i / 200, j = i % 200;
        int r = j / 25, k = j % 25;
        const float* w = (half ? w2 : w1) + (s * 8 + r) * 64;
        float acc = (half ? b2 : b1)[s * 8 + r];
        for (int c = 0; c < 64; c++) acc += w[c] * sm[5000 + c * 25 + k];
        sm[6600 + i] = acc;
    }
    __syncthreads();

    for (int i = tid; i < 5400; i += 512) {
        if (i < 5000) {
            int r = i / 625, uv = i % 625, u = uv / 25, v = uv % 25;
            sm[i] = tanhf(sm[6600 + r * 25 + u] - sm[6800 + r * 25 + v]);
        } else {
            int i2 = i - 5000;
            int half = i2 / 200, j = i2 % 200;
            int r = j / 25, k = j % 25;
            float acc = 0.f;
            for (int p = 0; p < 8; p++)
                acc += pw1[(s * 8 + r) * 16 + half * 8 + p] * sm[6800 + p * 25 + k];
            sm[7000 + i2] = acc;
        }
    }
    __syncthreads();

    for (int i = tid; i < 5000; i += 512) {
        int r = i / 625, uv = i % 625, u = uv / 25, v = uv % 25;
        float t = sm[7000 + r * 25 + u] + sm[7200 + r * 25 + v] + pb1[s * 8 + r];
        sm[10000 + i] = t > 0.f ? t : 0.f;
    }
    __syncthreads();

    for (int i = tid; i < 5000; i += 512) {
        int r = i / 625, uv = i % 625;
        float q2 = pb2[s * 8 + r];
        for (int p = 0; p < 8; p++)
            q2 += pw2[(s * 8 + r) * 8 + p] * sm[10000 + p * 625 + uv];
        sm[5000 + i] = sm[i] + gam * q2;
    }
    __syncthreads();

    for (int i = tid; i < 5000; i += 512) {
        int r = i / 625, uv = i % 625, u = uv / 25, v = uv % 25;
        float acc = 0.f;
        for (int di = 0; di < 3; di++) {
            int uu = u + di - 1;
            if (uu < 0 || uu > 24) continue;
            for (int dj = 0; dj < 3; dj++) {
                int vv = v + dj - 1;
                if (vv < 0 || vv > 24) continue;
                acc += sm[r * 625 + uu * 25 + vv] * dww[(s * 8 + r) * 9 + di * 3 + dj];
            }
        }
        sm[10000 + i] = acc;
    }
    __syncthreads();

    for (int i = tid; i < 5000; i += 512) {
        int r = i / 625, uv = i % 625, u = uv / 25, v = uv % 25;
        float acc = 0.f;
        for (int di = 0; di < 3; di++) {
            int uu = u + di - 1;
            if (uu < 0 || uu > 24) continue;
            for (int dj = 0; dj < 3; dj++) {
                int vv = v + dj - 1;
                if (vv < 0 || vv > 24) continue;
                acc += sm[10000 + r * 625 + uu * 25 + vv];
            }
        }
        sm[i] = tanhf(acc * (1.f / 9.f));
    }
    __syncthreads();

    unsigned short* Rb = Rg + (unsigned)((s * 64 + n)) * 44800u;
    for (int i = tid; i < 44800; i += 512) {
        int o = i / 700, uv = i % 700, uu = uv / 28, vv = uv % 28;
        unsigned short val = 0;
        if (vv < 25) {
            int quv = uu * 25 + vv;
            float mn = b4[s * 64 + o], aux = 0.f;
            for (int r = 0; r < 8; r++) {
                mn  += w4[(s * 64 + o) * 8 + r] * sm[5000 + r * 625 + quv];
                aux += pjw[(s * 64 + o) * 8 + r] * sm[r * 625 + quv];
            }
            val = f2bf(mn * alpha + A[s * 625 + quv] + bet * aux);
        }
        Rb[i] = val;
    }
}

// ---------------- K3: main fused kernel: both stages on MFMA ----------------
// block = (n, t-tile of 8); 2048 blocks; 256 thr = 4 waves; wave w owns o-chunk
// LDS (59,392 B, 2 blocks/CU): xb [200 tv][64 c] bf16 swizzled (25,600 B)
//   + X3 [64 o][8 t][16 w + 4 pad] uint (33,792 B) -- o-stride 132 words makes
//   both X3 b128 writes and reads bank-conflict-free (8 slots x 8 lanes).
// xb staged ONCE; X3 is wave-private (own o-chunk) -> s-loop has ZERO barriers.
// Stage-2 operand-swapped (A=X3, B=R) -> D=[t][u] -> contiguous 16-dword stores.
__global__ __launch_bounds__(256, 2) void k_main(
    const float* __restrict__ x, const float* __restrict__ w3,
    const float* __restrict__ b3, const unsigned short* __restrict__ Rg,
    float* __restrict__ out, float* __restrict__ bnacc) {
    __shared__ __align__(16) unsigned char smem[59392];
    unsigned short* xb = (unsigned short*)smem;        // [200][64] swizzled
    unsigned*       x3 = (unsigned*)(smem + 25600);    // [64 o][132 words]

    const int tid  = threadIdx.x;
    // XCD-chunked bijective swizzle (2048 % 8 == 0): XCD gets contiguous n-range
    const int blk  = ((int)blockIdx.x & 7) * 256 + ((int)blockIdx.x >> 3);
    const int n    = blk >> 5;
    const int t0   = (blk & 31) * 8;
    const int lane = tid & 63;
    const int w    = tid >> 6;          // wave id = o-chunk
    const int a    = lane & 15;
    const int q    = lane >> 4;         // quad
    const int og   = w * 16 + a;

    // ---- stage x[n, :, t0:t0+8, :] -> xb bf16, swizzled (ONCE) ----
    {
        const float* xbase = x + (unsigned)n * 409600u + t0 * 25;
        #pragma unroll
        for (int k = 0; k < 13; k++) {
            int i = tid + k * 256;       // 0..3199 (12800 ushorts / 4)
            if (i < 3200) {
                int tv = i % 200;        // t_local*25 + v
                int cq = i / 200;        // c-quad 0..15
                const float* p = xbase + cq * 4 * 6400 + tv;
                ushort4 h;
                h.x = f2bf(p[0]); h.y = f2bf(p[6400]);
                h.z = f2bf(p[12800]); h.w = f2bf(p[19200]);
                int addr = tv * 64 + (((cq >> 1) ^ (tv & 7)) << 3) + ((cq & 1) << 2);
                *(ushort4*)&xb[addr] = h;
            }
        }
    }
    __syncthreads();    // the ONLY barrier

    f32x4 yacc[16][2];                  // [o-in-chunk][u-tile]; accum across s
    #pragma unroll
    for (int k = 0; k < 16; k++) {
        yacc[k][0] = (f32x4){0.f, 0.f, 0.f, 0.f};
        yacc[k][1] = (f32x4){0.f, 0.f, 0.f, 0.f};
    }

    for (int s = 0; s < 3; s++) {
        // ---- w3^T B-frags + bias ----
        bf16x8 bfr[2];
        {
            const float* wp = w3 + (s * 64 + og) * 64;
            #pragma unroll
            for (int ks = 0; ks < 2; ks++)
                #pragma unroll
                for (int j = 0; j < 8; j++)
                    bfr[ks][j] = (short)f2bf(wp[ks * 32 + q * 8 + j]);
        }
        const float bias = b3[s * 64 + og];

        // ---- stage-1: X3[og][t][v] via MFMA over c; pack bf16 pairs on the fly.
        //      D rows t = q*4+r; only t<8 (q<2) valid (a>=8 xb rows are garbage,
        //      contained in discarded D rows). ----
        unsigned x3pk[13][4];
        #pragma unroll
        for (int i = 0; i < 12; i++) {
            f32x4 ca, cb;
            {
                const int row = a * 25 + 2 * i;
                const int sw  = row & 7;
                bf16x8 a0 = *(const bf16x8*)&xb[row * 64 + ((q ^ sw) << 3)];
                bf16x8 a1 = *(const bf16x8*)&xb[row * 64 + (((4 + q) ^ sw) << 3)];
                f32x4 c0; c0[0] = bias; c0[1] = bias; c0[2] = bias; c0[3] = bias;
                c0 = __builtin_amdgcn_mfma_f32_16x16x32_bf16(a0, bfr[0], c0, 0, 0, 0);
                ca = __builtin_amdgcn_mfma_f32_16x16x32_bf16(a1, bfr[1], c0, 0, 0, 0);
            }
            {
                const int row = a * 25 + 2 * i + 1;
                const int sw  = row & 7;
                bf16x8 a0 = *(const bf16x8*)&xb[row * 64 + ((q ^ sw) << 3)];
                bf16x8 a1 = *(const bf16x8*)&xb[row * 64 + (((4 + q) ^ sw) << 3)];
                f32x4 c0; c0[0] = bias; c0[1] = bias; c0[2] = bias; c0[3] = bias;
                c0 = __builtin_amdgcn_mfma_f32_16x16x32_bf16(a0, bfr[0], c0, 0, 0, 0);
                cb = __builtin_amdgcn_mfma_f32_16x16x32_bf16(a1, bfr[1], c0, 0, 0, 0);
            }
            #pragma unroll
            for (int r = 0; r < 4; r++) x3pk[i][r] = pk2(ca[r], cb[r]);
        }
        {
            const int row = a * 25 + 24;
            const int sw  = row & 7;
            bf16x8 a0 = *(const bf16x8*)&xb[row * 64 + ((q ^ sw) << 3)];
            bf16x8 a1 = *(const bf16x8*)&xb[row * 64 + (((4 + q) ^ sw) << 3)];
            f32x4 c0; c0[0] = bias; c0[1] = bias; c0[2] = bias; c0[3] = bias;
            c0 = __builtin_amdgcn_mfma_f32_16x16x32_bf16(a0, bfr[0], c0, 0, 0, 0);
            c0 = __builtin_amdgcn_mfma_f32_16x16x32_bf16(a1, bfr[1], c0, 0, 0, 0);
            #pragma unroll
            for (int r = 0; r < 4; r++) x3pk[12][r] = pk2(c0[r], 0.f);
        }

        // ---- write X3 to LDS [og][t=q*4+r][16 words], t<8 only (q<2) ----
        // wave-private rows; no barrier needed (in-wave lgkmcnt ordering)
        if (q < 2) {
            #pragma unroll
            for (int r = 0; r < 4; r++) {
                unsigned* dst = &x3[og * 132 + (q * 4 + r) * 16];
                u32x4 w0, w1, w2, wd;
                w0[0] = x3pk[0][r];  w0[1] = x3pk[1][r];
                w0[2] = x3pk[2][r];  w0[3] = x3pk[3][r];
                w1[0] = x3pk[4][r];  w1[1] = x3pk[5][r];
                w1[2] = x3pk[6][r];  w1[3] = x3pk[7][r];
                w2[0] = x3pk[8][r];  w2[1] = x3pk[9][r];
                w2[2] = x3pk[10][r]; w2[3] = x3pk[11][r];
                wd[0] = x3pk[12][r]; wd[1] = 0u; wd[2] = 0u; wd[3] = 0u;
                *(u32x4*)(dst)      = w0;
                *(u32x4*)(dst + 4)  = w1;
                *(u32x4*)(dst + 8)  = w2;
                *(u32x4*)(dst + 12) = wd;
            }
        }

        // ---- stage-2 (operand-swapped): y[t][u] += X3[o][t][v] * R[o][u][v] ----
        // A = X3 (lane a = t row, chunk q*8 = v), B = R (lane a = u col)
        const unsigned short* Rsn = Rg + (unsigned)((s * 64 + n)) * 44800u;
        #pragma unroll
        for (int k = 0; k < 16; k++) {
            const int o = w * 16 + k;
            bf16x8 Af = *(const bf16x8*)&x3[o * 132 + a * 16 + q * 4];
            const unsigned short* Ro = Rsn + o * 700;
            BFRU B0, B1;
            B0.d[0] = *(const u32x2*)(Ro + a * 28 + q * 8);
            B0.d[1] = *(const u32x2*)(Ro + a * 28 + q * 8 + 4);
            const int u1 = (a < 9) ? (16 + a) : 0;   // clamp: cols a>=9 discarded
            B1.d[0] = *(const u32x2*)(Ro + u1 * 28 + q * 8);
            B1.d[1] = *(const u32x2*)(Ro + u1 * 28 + q * 8 + 4);
            yacc[k][0] = __builtin_amdgcn_mfma_f32_16x16x32_bf16(Af, B0.v, yacc[k][0], 0, 0, 0);
            yacc[k][1] = __builtin_amdgcn_mfma_f32_16x16x32_bf16(Af, B1.v, yacc[k][1], 0, 0, 0);
        }
    }

    // ---- store y[n][o][t0+q*4+r][u] (contiguous 16-dword runs) + fused BN ----
    float* outb = out + (unsigned)(n * 64) * 6400u + t0 * 25;
    #pragma unroll
    for (int k = 0; k < 16; k++) {
        const int o = w * 16 + k;
        float* op = outb + o * 6400;
        float s1 = 0.f, s2 = 0.f;
        if (q < 2) {
            #pragma unroll
            for (int r = 0; r < 4; r++) {
                float v0 = yacc[k][0][r];          // u = a
                op[(q * 4 + r) * 25 + a] = v0;
                s1 += v0; s2 += v0 * v0;
                if (a < 9) {
                    float v1 = yacc[k][1][r];      // u = 16+a
                    op[(q * 4 + r) * 25 + 16 + a] = v1;
                    s1 += v1; s2 += v1 * v1;
                }
            }
        }
        #pragma unroll
        for (int off = 1; off < 64; off <<= 1) {
            s1 += __shfl_xor(s1, off);
            s2 += __shfl_xor(s2, off);
        }
        if (lane == 0) {
            atomicAdd(&bnacc[o * 16], s1);             // 64B-strided slots
            atomicAdd(&bnacc[1024 + o * 16], s2);
        }
    }
}

// ---------------- K5: normalize + residual + relu ----------------
__global__ __launch_bounds__(256) void k_final(
    float* __restrict__ out, const float* __restrict__ x,
    const float* __restrict__ bnacc,
    const float* __restrict__ bnw, const float* __restrict__ bnb) {
    const int idx4 = blockIdx.x * 256 + threadIdx.x;   // < 6,553,600
    const int o = (idx4 / 1600) & 63;
    const float cnt = 1.f / 409600.f;
    float mean = bnacc[o * 16] * cnt;
    float var = bnacc[1024 + o * 16] * cnt - mean * mean;
    float inv = rsqrtf(var + 1e-5f);
    float sc = bnw[o] * inv;
    float sh = bnb[o] - mean * sc;
    float4 y = ((const float4*)out)[idx4];
    float4 xv = ((const float4*)x)[idx4];
    y.x = fmaxf(y.x * sc + sh + xv.x, 0.f);
    y.y = fmaxf(y.y * sc + sh + xv.y, 0.f);
    y.z = fmaxf(y.z * sc + sh + xv.z, 0.f);
    y.w = fmaxf(y.w * sc + sh + xv.w, 0.f);
    ((float4*)out)[idx4] = y;
}

extern "C" void kernel_launch(void* const* d_in, const int* in_sizes, int n_in,
                              void* d_out, int out_size, void* d_ws, size_t ws_size,
                              hipStream_t stream) {
    const float* x     = (const float*)d_in[0];
    const float* A     = (const float*)d_in[1];
    const float* alpha = (const float*)d_in[2];
    const float* w1    = (const float*)d_in[3];
    const float* b1    = (const float*)d_in[4];
    const float* w2    = (const float*)d_in[5];
    const float* b2    = (const float*)d_in[6];
    const float* w3    = (const float*)d_in[7];
    const float* b3    = (const float*)d_in[8];
    const float* w4    = (const float*)d_in[9];
    const float* b4    = (const float*)d_in[10];
    const float* pw1   = (const float*)d_in[11];
    const float* pb1   = (const float*)d_in[12];
    const float* pw2   = (const float*)d_in[13];
    const float* pb2   = (const float*)d_in[14];
    const float* dww   = (const float*)d_in[15];
    const float* pjw   = (const float*)d_in[16];
    const float* beta  = (const float*)d_in[17];
    const float* gamma = (const float*)d_in[18];
    const float* bnw   = (const float*)d_in[19];
    const float* bnb   = (const float*)d_in[20];
    float* out = (float*)d_out;
    float* ws  = (float*)d_ws;
    unsigned short* wsR = (unsigned short*)((char*)d_ws + WS_R_BYTE);
    float* wsBN = ws;   // overlaps xm region; memset after k_small has consumed xm

    k_xm<<<4096, 256, 0, stream>>>(x, ws);
    k_small<<<192, 512, 0, stream>>>(ws, wsR, A, alpha, w1, b1, w2, b2,
                                     w4, b4, pw1, pb1, pw2, pb2, dww, pjw,
                                     beta, gamma);
    hipMemsetAsync(wsBN, 0, 8192, stream);
    k_main<<<2048, 256, 0, stream>>>(x, w3, b3, wsR, out, wsBN);
    k_final<<<25600, 256, 0, stream>>>(out, x, wsBN, bnw, bnb);
}

// Round 5
// 434.016 us; speedup vs baseline: 1.4127x; 1.4127x over previous
//
#include <hip/hip_runtime.h>

// N=64, CIN=COUT=64, T=256, V=25, S=3, REL=8
// ws layout (bytes):
//   [0, 8192)                : BN stats: sum at [o*16], sumsq at [1024 + o*16] (fp32)
//                              (overlaps xm region; memset AFTER k_small has consumed xm)
//   [0, 409600)              : xm[n][c][v] fp32 (102400 floats) -- k_xm -> k_small only
//   [409600, +17203200)      : R_bf16[s][n][vg][o][row84]:
//                                vg<8 : block at vg*5376 ushorts, row = [o][iv*28+u] (3 v's)
//                                vg=8 : block at 43008, row = [o][u28] (1 v, v=24)
//                              u pad 25..27 = 0. Slab = 44800 ushorts per (s,n) (unchanged).
//                              (+512B DMA read-overrun at region end, within proven ws bound)

#define WS_R_BYTE   409600

typedef __attribute__((ext_vector_type(8))) short bf16x8;
typedef __attribute__((ext_vector_type(4))) float f32x4;

typedef __attribute__((address_space(1))) unsigned int uint_g;
typedef __attribute__((address_space(3))) unsigned int uint_l;

static __device__ __forceinline__ unsigned short f2bf(float f) {
    unsigned int u = __float_as_uint(f);
    u += 0x7fff + ((u >> 16) & 1);          // RNE (finite values) -- harness-verified
    return (unsigned short)(u >> 16);
}
static __device__ __forceinline__ float bf2f(unsigned short s) {
    return __uint_as_float(((unsigned int)s) << 16);
}
// async global->LDS, 16B per lane: LDS dest = wave-uniform base + lane*16
static __device__ __forceinline__ void gload_lds16(const void* g, void* l) {
    __builtin_amdgcn_global_load_lds((const uint_g*)g, (uint_l*)l, 16, 0, 0);
}

// ---------------- K1: xm = mean over T (coalesced) ----------------
__global__ __launch_bounds__(256) void k_xm(const float* __restrict__ x,
                                            float* __restrict__ ws) {
    __shared__ float sm[6400];
    __shared__ float part[200];
    const int tid = threadIdx.x;
    const int n = blockIdx.x >> 6, c = blockIdx.x & 63;
    const float4* p = (const float4*)(x + (unsigned)(n * 64 + c) * 6400u);
    float4* s4 = (float4*)sm;
    for (int i = tid; i < 1600; i += 256) s4[i] = p[i];
    __syncthreads();
    if (tid < 200) {
        int v = tid % 25, g = tid / 25;
        float s = 0.f;
        for (int tt = 0; tt < 32; tt++) s += sm[(g * 32 + tt) * 25 + v];
        part[tid] = s;
    }
    __syncthreads();
    if (tid < 25) {
        float s = 0.f;
        #pragma unroll
        for (int g = 0; g < 8; g++) s += part[g * 25 + tid];
        ws[n * 1600 + c * 25 + tid] = s * (1.f / 256.f);
    }
}

// ---------------- K2: build R_bf16 (vg-grouped layout) ----------------
__global__ __launch_bounds__(512) void k_small(
    const float* __restrict__ ws, unsigned short* __restrict__ Rg,
    const float* __restrict__ A, const float* __restrict__ alphap,
    const float* __restrict__ w1, const float* __restrict__ b1,
    const float* __restrict__ w2, const float* __restrict__ b2,
    const float* __restrict__ w4, const float* __restrict__ b4,
    const float* __restrict__ pw1, const float* __restrict__ pb1,
    const float* __restrict__ pw2, const float* __restrict__ pb2,
    const float* __restrict__ dww, const float* __restrict__ pjw,
    const float* __restrict__ beta, const float* __restrict__ gamma) {
    __shared__ float sm[15000];
    const int tid = threadIdx.x;
    const int s = blockIdx.x >> 6;   // 0..2
    const int n = blockIdx.x & 63;   // 0..63
    const float alpha = alphap[0];
    const float gam = gamma[s], bet = beta[s];

    for (int i = tid; i < 1600; i += 512) sm[5000 + i] = ws[n * 1600 + i];
    __syncthreads();

    for (int i = tid; i < 400; i += 512) {
        int half = i / 200, j = i % 200;
        int r = j / 25, k = j % 25;
        const float* w = (half ? w2 : w1) + (s * 8 + r) * 64;
        float acc = (half ? b2 : b1)[s * 8 + r];
        for (int c = 0; c < 64; c++) acc += w[c] * sm[5000 + c * 25 + k];
        sm[6600 + i] = acc;
    }
    __syncthreads();

    for (int i = tid; i < 5400; i += 512) {
        if (i < 5000) {
            int r = i / 625, uv = i % 625, u = uv / 25, v = uv % 25;
            sm[i] = tanhf(sm[6600 + r * 25 + u] - sm[6800 + r * 25 + v]);
        } else {
            int i2 = i - 5000;
            int half = i2 / 200, j = i2 % 200;
            int r = j / 25, k = j % 25;
            float acc = 0.f;
            for (int p = 0; p < 8; p++)
                acc += pw1[(s * 8 + r) * 16 + half * 8 + p] * sm[6800 + p * 25 + k];
            sm[7000 + i2] = acc;
        }
    }
    __syncthreads();

    for (int i = tid; i < 5000; i += 512) {
        int r = i / 625, uv = i % 625, u = uv / 25, v = uv % 25;
        float t = sm[7000 + r * 25 + u] + sm[7200 + r * 25 + v] + pb1[s * 8 + r];
        sm[10000 + i] = t > 0.f ? t : 0.f;
    }
    __syncthreads();

    for (int i = tid; i < 5000; i += 512) {
        int r = i / 625, uv = i % 625;
        float q2 = pb2[s * 8 + r];
        for (int p = 0; p < 8; p++)
            q2 += pw2[(s * 8 + r) * 8 + p] * sm[10000 + p * 625 + uv];
        sm[5000 + i] = sm[i] + gam * q2;
    }
    __syncthreads();

    for (int i = tid; i < 5000; i += 512) {
        int r = i / 625, uv = i % 625, u = uv / 25, v = uv % 25;
        float acc = 0.f;
        for (int di = 0; di < 3; di++) {
            int uu = u + di - 1;
            if (uu < 0 || uu > 24) continue;
            for (int dj = 0; dj < 3; dj++) {
                int vv = v + dj - 1;
                if (vv < 0 || vv > 24) continue;
                acc += sm[r * 625 + uu * 25 + vv] * dww[(s * 8 + r) * 9 + di * 3 + dj];
            }
        }
        sm[10000 + i] = acc;
    }
    __syncthreads();

    for (int i = tid; i < 5000; i += 512) {
        int r = i / 625, uv = i % 625, u = uv / 25, v = uv % 25;
        float acc = 0.f;
        for (int di = 0; di < 3; di++) {
            int uu = u + di - 1;
            if (uu < 0 || uu > 24) continue;
            for (int dj = 0; dj < 3; dj++) {
                int vv = v + dj - 1;
                if (vv < 0 || vv > 24) continue;
                acc += sm[10000 + r * 625 + uu * 25 + vv];
            }
        }
        sm[i] = tanhf(acc * (1.f / 9.f));
    }
    __syncthreads();

    // R value at (o, v, u) stored into vg-grouped layout (see header comment)
    unsigned short* Rb = Rg + (unsigned)(s * 64 + n) * 44800u;
    for (int i = tid; i < 44800; i += 512) {
        int o, vv, uu;
        if (i < 43008) {
            int vg = i / 5376, rem = i % 5376;
            o = rem / 84;
            int j = rem % 84;
            vv = vg * 3 + j / 28;
            uu = j % 28;
        } else {
            int rem = i - 43008;
            o = rem / 28;
            vv = 24;
            uu = rem % 28;
        }
        unsigned short val = 0;
        if (uu < 25) {
            int quv = uu * 25 + vv;     // [u][v] index into q_all / pool
            float mn = b4[s * 64 + o], aux = 0.f;
            for (int r = 0; r < 8; r++) {
                mn  += w4[(s * 64 + o) * 8 + r] * sm[5000 + r * 625 + quv];
                aux += pjw[(s * 64 + o) * 8 + r] * sm[r * 625 + quv];
            }
            val = f2bf(mn * alpha + A[s * 625 + quv] + bet * aux);
        }
        Rb[i] = val;
    }
}

// ---------------- K3: main fused kernel (r0 structure + DMA-pipelined Rs) ----------------
// block = (n, t-tile of 16); 1024 blocks; 256 thr = 4 waves; wave w = o-chunk [w*16,+16)
// LDS 73728 B (2 blocks/CU): xb[400][64] bf16 swizzled (51200) + Rs dbuf 2x11264.
// Pipeline: issue global_load_lds for NEXT (s,vg) into buf^1 -> compute current from
// buf (MFMA stage-1 + VALU stage-2, r0-verbatim) -> __syncthreads (drains DMA) -> swap.
// One barrier per iteration; R loads hidden under ~800cy of compute.
__global__ __launch_bounds__(256, 2) void k_main(
    const float* __restrict__ x, const float* __restrict__ w3,
    const float* __restrict__ b3, const unsigned short* __restrict__ Rg,
    float* __restrict__ out, float* __restrict__ bnacc) {
    __shared__ __align__(16) unsigned char smem[73728];
    unsigned short* xb = (unsigned short*)smem;        // [tv 400][c 64] swizzled
    unsigned char* RsBase = smem + 51200;              // 2 x 11264 B

    const int tid  = threadIdx.x;
    // XCD-chunked bijective swizzle (1024 % 8 == 0): each XCD gets 8 contiguous n's
    const int blk  = ((int)blockIdx.x & 7) * 128 + ((int)blockIdx.x >> 3);
    const int n    = blk >> 4;
    const int t0   = (blk & 15) * 16;
    const int lane = tid & 63;
    const int w    = tid >> 6;          // wave id = o-chunk
    const int ln15 = lane & 15;
    const int q    = lane >> 4;         // quad
    const int og   = w * 16 + ln15;     // this lane's o

    const unsigned short* Rn0 = Rg;     // base; per-(s) slab offset added in stage

    // ---- issue DMA stage of (s=0, vg=0) into buf 0 (overlaps xb staging below) ----
    {
        const char* src = (const char*)Rg + (size_t)((0 * 64 + n) * 44800) * 2;   // vg0
        unsigned char* dst = RsBase;    // buf 0
        for (int j = w; j < 11; j += 4)
            gload_lds16(src + j * 1024 + (lane << 4), dst + j * 1024);
    }

    // ---- stage x[n, :, t0:t0+16, :] -> xb bf16, swizzled (r0-verbatim, ONCE) ----
    {
        const float* xbase = x + n * 409600 + t0 * 25;
        #pragma unroll 5
        for (int k = 0; k < 25; k++) {
            int i  = tid + k * 256;      // 0..6399
            int tv = i % 400;
            int cq = i / 400;            // c-quad 0..15
            const float* p = xbase + cq * 4 * 6400 + tv;
            ushort4 h;
            h.x = f2bf(p[0]); h.y = f2bf(p[6400]);
            h.z = f2bf(p[12800]); h.w = f2bf(p[19200]);
            int addr = tv * 64 + (((cq >> 1) ^ (tv & 7)) << 3) + ((cq & 1) << 2);
            *(ushort4*)&xb[addr] = h;
        }
    }
    __syncthreads();    // xb visible + buf0 DMA complete

    float yacc[25][4];
    #pragma unroll
    for (int u = 0; u < 25; u++)
        #pragma unroll
        for (int r = 0; r < 4; r++) yacc[u][r] = 0.f;

    int buf = 0;
    for (int s = 0; s < 3; s++) {
        // B-frags (w3^T) + bias for this (s, og)  -- r0-verbatim
        bf16x8 bfr[2];
        {
            const float* wp = w3 + (s * 64 + og) * 64;
            #pragma unroll
            for (int ks = 0; ks < 2; ks++)
                #pragma unroll
                for (int j = 0; j < 8; j++)
                    bfr[ks][j] = (short)f2bf(wp[ks * 32 + q * 8 + j]);
        }
        const float bias = b3[s * 64 + og];

        for (int vg = 0; vg < 9; vg++) {
            // ---- issue DMA prefetch of the NEXT (s,vg) into buf^1 ----
            {
                int ns = s, nvg = vg + 1;
                if (nvg == 9) { ns = s + 1; nvg = 0; }
                if (ns < 3) {
                    const char* src = (const char*)Rg +
                        (size_t)((ns * 64 + n) * 44800 + nvg * 5376) * 2;
                    unsigned char* dst = RsBase + (buf ^ 1) * 11264;
                    const int rounds = (nvg < 8) ? 11 : 4;
                    for (int j = w; j < rounds; j += 4)
                        gload_lds16(src + j * 1024 + (lane << 4), dst + j * 1024);
                }
            }

            const unsigned short* RsB = (const unsigned short*)(RsBase + buf * 11264);
            const int nv = (vg < 8) ? 3 : 1;

            // stage 1: X3 C-frags for the nv v's of this group (MFMA) -- r0-verbatim
            f32x4 c[3];
            #pragma unroll
            for (int iv = 0; iv < 3; iv++) {
                if (iv >= nv) break;
                const int v   = vg * 3 + iv;
                const int row = ln15 * 25 + v;
                const int sw  = row & 7;
                bf16x8 a0 = *(const bf16x8*)&xb[row * 64 + ((q ^ sw) << 3)];
                bf16x8 a1 = *(const bf16x8*)&xb[row * 64 + (((4 + q) ^ sw) << 3)];
                f32x4 cc; cc[0] = bias; cc[1] = bias; cc[2] = bias; cc[3] = bias;
                cc = __builtin_amdgcn_mfma_f32_16x16x32_bf16(a0, bfr[0], cc, 0, 0, 0);
                cc = __builtin_amdgcn_mfma_f32_16x16x32_bf16(a1, bfr[1], cc, 0, 0, 0);
                c[iv] = cc;
            }
            // stage 2: y[u][t-reg] += R[og][v][u] * X3 (fp32 VALU) -- r0-verbatim
            #pragma unroll
            for (int iv = 0; iv < 3; iv++) {
                if (iv >= nv) break;
                const unsigned short* rr = (vg < 8) ? &RsB[og * 84 + iv * 28]
                                                    : &RsB[og * 28];
                f32x4 cc = c[iv];
                #pragma unroll
                for (int ug = 0; ug < 6; ug++) {
                    ushort4 r4 = *(const ushort4*)(rr + ug * 4);
                    float f0 = bf2f(r4.x), f1 = bf2f(r4.y);
                    float f2 = bf2f(r4.z), f3 = bf2f(r4.w);
                    #pragma unroll
                    for (int r = 0; r < 4; r++) {
                        yacc[ug * 4 + 0][r] += f0 * cc[r];
                        yacc[ug * 4 + 1][r] += f1 * cc[r];
                        yacc[ug * 4 + 2][r] += f2 * cc[r];
                        yacc[ug * 4 + 3][r] += f3 * cc[r];
                    }
                }
                float f24 = bf2f(rr[24]);
                #pragma unroll
                for (int r = 0; r < 4; r++) yacc[24][r] += f24 * cc[r];
            }

            __syncthreads();   // drains prefetch DMA + all waves done with buf
            buf ^= 1;
        }
    }

    // ---- store y[n][og][t0 + q*4 + r][u] (r0-verbatim scalar dwords) + fused BN ----
    float* op = out + (n * 64 + og) * 6400 + t0 * 25;
    float s1 = 0.f, s2 = 0.f;
    #pragma unroll
    for (int r = 0; r < 4; r++) {
        float* opr = op + (q * 4 + r) * 25;
        #pragma unroll
        for (int u = 0; u < 25; u++) {
            float vv = yacc[u][r];
            opr[u] = vv;
            s1 += vv; s2 += vv * vv;
        }
    }
    s1 += __shfl_xor(s1, 16); s1 += __shfl_xor(s1, 32);
    s2 += __shfl_xor(s2, 16); s2 += __shfl_xor(s2, 32);
    if (q == 0) {
        atomicAdd(&bnacc[og * 16], s1);             // 64B-strided slots
        atomicAdd(&bnacc[1024 + og * 16], s2);
    }
}

// ---------------- K5: normalize + residual + relu ----------------
__global__ __launch_bounds__(256) void k_final(
    float* __restrict__ out, const float* __restrict__ x,
    const float* __restrict__ bnacc,
    const float* __restrict__ bnw, const float* __restrict__ bnb) {
    const int idx4 = blockIdx.x * 256 + threadIdx.x;   // < 6,553,600
    const int o = (idx4 / 1600) & 63;
    const float cnt = 1.f / 409600.f;
    float mean = bnacc[o * 16] * cnt;
    float var = bnacc[1024 + o * 16] * cnt - mean * mean;
    float inv = rsqrtf(var + 1e-5f);
    float sc = bnw[o] * inv;
    float sh = bnb[o] - mean * sc;
    float4 y = ((const float4*)out)[idx4];
    float4 xv = ((const float4*)x)[idx4];
    y.x = fmaxf(y.x * sc + sh + xv.x, 0.f);
    y.y = fmaxf(y.y * sc + sh + xv.y, 0.f);
    y.z = fmaxf(y.z * sc + sh + xv.z, 0.f);
    y.w = fmaxf(y.w * sc + sh + xv.w, 0.f);
    ((float4*)out)[idx4] = y;
}

extern "C" void kernel_launch(void* const* d_in, const int* in_sizes, int n_in,
                              void* d_out, int out_size, void* d_ws, size_t ws_size,
                              hipStream_t stream) {
    const float* x     = (const float*)d_in[0];
    const float* A     = (const float*)d_in[1];
    const float* alpha = (const float*)d_in[2];
    const float* w1    = (const float*)d_in[3];
    const float* b1    = (const float*)d_in[4];
    const float* w2    = (const float*)d_in[5];
    const float* b2    = (const float*)d_in[6];
    const float* w3    = (const float*)d_in[7];
    const float* b3    = (const float*)d_in[8];
    const float* w4    = (const float*)d_in[9];
    const float* b4    = (const float*)d_in[10];
    const float* pw1   = (const float*)d_in[11];
    const float* pb1   = (const float*)d_in[12];
    const float* pw2   = (const float*)d_in[13];
    const float* pb2   = (const float*)d_in[14];
    const float* dww   = (const float*)d_in[15];
    const float* pjw   = (const float*)d_in[16];
    const float* beta  = (const float*)d_in[17];
    const float* gamma = (const float*)d_in[18];
    const float* bnw   = (const float*)d_in[19];
    const float* bnb   = (const float*)d_in[20];
    float* out = (float*)d_out;
    float* ws  = (float*)d_ws;
    unsigned short* wsR = (unsigned short*)((char*)d_ws + WS_R_BYTE);
    float* wsBN = ws;   // overlaps xm region; memset after k_small has consumed xm

    k_xm<<<4096, 256, 0, stream>>>(x, ws);
    k_small<<<192, 512, 0, stream>>>(ws, wsR, A, alpha, w1, b1, w2, b2,
                                     w4, b4, pw1, pb1, pw2, pb2, dww, pjw,
                                     beta, gamma);
    hipMemsetAsync(wsBN, 0, 8192, stream);
    k_main<<<1024, 256, 0, stream>>>(x, w3, b3, wsR, out, wsBN);
    k_final<<<25600, 256, 0, stream>>>(out, x, wsBN, bnw, bnb);
}

// Round 6
// 429.547 us; speedup vs baseline: 1.4274x; 1.0104x over previous
//
#include <hip/hip_runtime.h>

// N=64, CIN=COUT=64, T=256, V=25, S=3, REL=8
// ws layout (bytes):
//   [0, 409600)              : xm[n][c][v] fp32 (102400 floats) -- k_xm -> k_small only
//   [409600, +17203200)      : R_bf16[s][n] slabs of 44800 ushorts, grouped:
//                                vg<7 : offset vg*5376, [o64][84]  (3 v's: v=vg*3+j/28, u=j%28)
//                                vg=7 : offset 37632,  [o64][112] (4 v's: v=21+j/28)
//                              u pad 25..27 = 0.  (no DMA overrun: stages end exactly at slab end)
//   [17612800, +8192)        : BN stats: sum at [o*16], sumsq at [2048 + o*16] bytes... (fp32,
//                              64B-strided slots); zeroed by k_xm block 0. End 17620992 <= proven bound.

#define WS_R_BYTE   409600
#define WS_BN_BYTE  17612800

typedef __attribute__((ext_vector_type(8))) short bf16x8;
typedef __attribute__((ext_vector_type(4))) float f32x4;
typedef __attribute__((ext_vector_type(2))) float f32x2;

typedef __attribute__((address_space(1))) unsigned int uint_g;
typedef __attribute__((address_space(3))) unsigned int uint_l;

static __device__ __forceinline__ unsigned short f2bf(float f) {
    unsigned int u = __float_as_uint(f);
    u += 0x7fff + ((u >> 16) & 1);          // RNE (finite values) -- harness-verified
    return (unsigned short)(u >> 16);
}
static __device__ __forceinline__ float bf2f(unsigned short s) {
    return __uint_as_float(((unsigned int)s) << 16);
}
// async global->LDS, 16B per lane: LDS dest = wave-uniform base + lane*16
static __device__ __forceinline__ void gload_lds16(const void* g, void* l) {
    __builtin_amdgcn_global_load_lds((const uint_g*)g, (uint_l*)l, 16, 0, 0);
}

// ---------------- K1: xm = mean over T (coalesced) + bnacc zero ----------------
__global__ __launch_bounds__(256) void k_xm(const float* __restrict__ x,
                                            float* __restrict__ ws,
                                            float* __restrict__ bnacc) {
    __shared__ float sm[6400];
    __shared__ float part[200];
    const int tid = threadIdx.x;
    if (blockIdx.x == 0) {
        for (int i = tid; i < 2048; i += 256) bnacc[i] = 0.f;
    }
    const int n = blockIdx.x >> 6, c = blockIdx.x & 63;
    const float4* p = (const float4*)(x + (unsigned)(n * 64 + c) * 6400u);
    float4* s4 = (float4*)sm;
    for (int i = tid; i < 1600; i += 256) s4[i] = p[i];
    __syncthreads();
    if (tid < 200) {
        int v = tid % 25, g = tid / 25;
        float s = 0.f;
        for (int tt = 0; tt < 32; tt++) s += sm[(g * 32 + tt) * 25 + v];
        part[tid] = s;
    }
    __syncthreads();
    if (tid < 25) {
        float s = 0.f;
        #pragma unroll
        for (int g = 0; g < 8; g++) s += part[g * 25 + tid];
        ws[n * 1600 + c * 25 + tid] = s * (1.f / 256.f);
    }
}

// ---------------- K2: build R_bf16 (vg-grouped layout, 7x3 + 1x4) ----------------
__global__ __launch_bounds__(512) void k_small(
    const float* __restrict__ ws, unsigned short* __restrict__ Rg,
    const float* __restrict__ A, const float* __restrict__ alphap,
    const float* __restrict__ w1, const float* __restrict__ b1,
    const float* __restrict__ w2, const float* __restrict__ b2,
    const float* __restrict__ w4, const float* __restrict__ b4,
    const float* __restrict__ pw1, const float* __restrict__ pb1,
    const float* __restrict__ pw2, const float* __restrict__ pb2,
    const float* __restrict__ dww, const float* __restrict__ pjw,
    const float* __restrict__ beta, const float* __restrict__ gamma) {
    __shared__ float sm[15000];
    const int tid = threadIdx.x;
    const int s = blockIdx.x >> 6;   // 0..2
    const int n = blockIdx.x & 63;   // 0..63
    const float alpha = alphap[0];
    const float gam = gamma[s], bet = beta[s];

    for (int i = tid; i < 1600; i += 512) sm[5000 + i] = ws[n * 1600 + i];
    __syncthreads();

    for (int i = tid; i < 400; i += 512) {
        int half = i / 200, j = i % 200;
        int r = j / 25, k = j % 25;
        const float* w = (half ? w2 : w1) + (s * 8 + r) * 64;
        float acc = (half ? b2 : b1)[s * 8 + r];
        for (int c = 0; c < 64; c++) acc += w[c] * sm[5000 + c * 25 + k];
        sm[6600 + i] = acc;
    }
    __syncthreads();

    for (int i = tid; i < 5400; i += 512) {
        if (i < 5000) {
            int r = i / 625, uv = i % 625, u = uv / 25, v = uv % 25;
            sm[i] = tanhf(sm[6600 + r * 25 + u] - sm[6800 + r * 25 + v]);
        } else {
            int i2 = i - 5000;
            int half = i2 / 200, j = i2 % 200;
            int r = j / 25, k = j % 25;
            float acc = 0.f;
            for (int p = 0; p < 8; p++)
                acc += pw1[(s * 8 + r) * 16 + half * 8 + p] * sm[6800 + p * 25 + k];
            sm[7000 + i2] = acc;
        }
    }
    __syncthreads();

    for (int i = tid; i < 5000; i += 512) {
        int r = i / 625, uv = i % 625, u = uv / 25, v = uv % 25;
        float t = sm[7000 + r * 25 + u] + sm[7200 + r * 25 + v] + pb1[s * 8 + r];
        sm[10000 + i] = t > 0.f ? t : 0.f;
    }
    __syncthreads();

    for (int i = tid; i < 5000; i += 512) {
        int r = i / 625, uv = i % 625;
        float q2 = pb2[s * 8 + r];
        for (int p = 0; p < 8; p++)
            q2 += pw2[(s * 8 + r) * 8 + p] * sm[10000 + p * 625 + uv];
        sm[5000 + i] = sm[i] + gam * q2;
    }
    __syncthreads();

    for (int i = tid; i < 5000; i += 512) {
        int r = i / 625, uv = i % 625, u = uv / 25, v = uv % 25;
        float acc = 0.f;
        for (int di = 0; di < 3; di++) {
            int uu = u + di - 1;
            if (uu < 0 || uu > 24) continue;
            for (int dj = 0; dj < 3; dj++) {
                int vv = v + dj - 1;
                if (vv < 0 || vv > 24) continue;
                acc += sm[r * 625 + uu * 25 + vv] * dww[(s * 8 + r) * 9 + di * 3 + dj];
            }
        }
        sm[10000 + i] = acc;
    }
    __syncthreads();

    for (int i = tid; i < 5000; i += 512) {
        int r = i / 625, uv = i % 625, u = uv / 25, v = uv % 25;
        float acc = 0.f;
        for (int di = 0; di < 3; di++) {
            int uu = u + di - 1;
            if (uu < 0 || uu > 24) continue;
            for (int dj = 0; dj < 3; dj++) {
                int vv = v + dj - 1;
                if (vv < 0 || vv > 24) continue;
                acc += sm[10000 + r * 625 + uu * 25 + vv];
            }
        }
        sm[i] = tanhf(acc * (1.f / 9.f));
    }
    __syncthreads();

    // R value at (o, v, u) stored into vg-grouped layout (see header comment)
    unsigned short* Rb = Rg + (unsigned)(s * 64 + n) * 44800u;
    for (int i = tid; i < 44800; i += 512) {
        int o, vv, uu;
        if (i < 37632) {
            int vg = i / 5376, rem = i % 5376;
            o = rem / 84;
            int j = rem % 84;
            vv = vg * 3 + j / 28;
            uu = j % 28;
        } else {
            int rem = i - 37632;
            o = rem / 112;
            int j = rem % 112;
            vv = 21 + j / 28;
            uu = j % 28;
        }
        unsigned short val = 0;
        if (uu < 25) {
            int quv = uu * 25 + vv;     // [u][v] index into q_all / pool
            float mn = b4[s * 64 + o], aux = 0.f;
            for (int r = 0; r < 8; r++) {
                mn  += w4[(s * 64 + o) * 8 + r] * sm[5000 + r * 625 + quv];
                aux += pjw[(s * 64 + o) * 8 + r] * sm[r * 625 + quv];
            }
            val = f2bf(mn * alpha + A[s * 625 + quv] + bet * aux);
        }
        Rb[i] = val;
    }
}

// ---------------- K3: main fused kernel (r5 structure + pk_fma stage-2) ----------------
// block = (n, t-tile of 16); 1024 blocks; 256 thr = 4 waves; wave w = o-chunk [w*16,+16)
// LDS 79872 B (2 blocks/CU): xb[400][64] bf16 swizzled (51200) + Rs dbuf 2x14336.
// 24 iterations (8 v-groups x 3 s), one barrier each; DMA prefetch of next group
// issued before compute, drained by the end-of-iteration barrier.
// Stage-2 accumulators are f32x2 pairs -> v_pk_fma_f32 (halves FMA issue count).
__global__ __launch_bounds__(256, 2) void k_main(
    const float* __restrict__ x, const float* __restrict__ w3,
    const float* __restrict__ b3, const unsigned short* __restrict__ Rg,
    float* __restrict__ out, float* __restrict__ bnacc) {
    __shared__ __align__(16) unsigned char smem[79872];
    unsigned short* xb = (unsigned short*)smem;        // [tv 400][c 64] swizzled
    unsigned char* RsBase = smem + 51200;              // 2 x 14336 B

    const int tid  = threadIdx.x;
    // XCD-chunked bijective swizzle (1024 % 8 == 0): each XCD gets 8 contiguous n's
    const int blk  = ((int)blockIdx.x & 7) * 128 + ((int)blockIdx.x >> 3);
    const int n    = blk >> 4;
    const int t0   = (blk & 15) * 16;
    const int lane = tid & 63;
    const int w    = tid >> 6;          // wave id = o-chunk
    const int ln15 = lane & 15;
    const int q    = lane >> 4;         // quad
    const int og   = w * 16 + ln15;     // this lane's o

    // ---- issue DMA stage of (s=0, vg=0) into buf 0 (overlaps xb staging below) ----
    {
        const char* src = (const char*)Rg + (size_t)(n * 44800) * 2;   // s0, vg0
        unsigned char* dst = RsBase;    // buf 0
        for (int j = w; j < 11; j += 4)
            gload_lds16(src + j * 1024 + (lane << 4), dst + j * 1024);
    }

    // ---- stage x[n, :, t0:t0+16, :] -> xb bf16, swizzled (ONCE) ----
    {
        const float* xbase = x + n * 409600 + t0 * 25;
        #pragma unroll 5
        for (int k = 0; k < 25; k++) {
            int i  = tid + k * 256;      // 0..6399
            int tv = i % 400;
            int cq = i / 400;            // c-quad 0..15
            const float* p = xbase + cq * 4 * 6400 + tv;
            ushort4 h;
            h.x = f2bf(p[0]); h.y = f2bf(p[6400]);
            h.z = f2bf(p[12800]); h.w = f2bf(p[19200]);
            int addr = tv * 64 + (((cq >> 1) ^ (tv & 7)) << 3) + ((cq & 1) << 2);
            *(ushort4*)&xb[addr] = h;
        }
    }
    __syncthreads();    // xb visible + buf0 DMA complete

    // yacc[u][h] : f32x2 over t-reg pairs (h=0: r0,r1 ; h=1: r2,r3)
    f32x2 yacc[25][2];
    #pragma unroll
    for (int u = 0; u < 25; u++) {
        yacc[u][0] = (f32x2){0.f, 0.f};
        yacc[u][1] = (f32x2){0.f, 0.f};
    }

    int buf = 0;
    for (int s = 0; s < 3; s++) {
        // B-frags (w3^T) + bias for this (s, og)
        bf16x8 bfr[2];
        {
            const float* wp = w3 + (s * 64 + og) * 64;
            #pragma unroll
            for (int ks = 0; ks < 2; ks++)
                #pragma unroll
                for (int j = 0; j < 8; j++)
                    bfr[ks][j] = (short)f2bf(wp[ks * 32 + q * 8 + j]);
        }
        const float bias = b3[s * 64 + og];

        for (int vg = 0; vg < 8; vg++) {
            // ---- issue DMA prefetch of the NEXT (s,vg) into buf^1 ----
            {
                int ns = s, nvg = vg + 1;
                if (nvg == 8) { ns = s + 1; nvg = 0; }
                if (ns < 3) {
                    const char* src = (const char*)Rg +
                        (size_t)((ns * 64 + n) * 44800 + nvg * 5376) * 2;
                    unsigned char* dst = RsBase + (buf ^ 1) * 14336;
                    const int rounds = (nvg < 7) ? 11 : 14;
                    for (int j = w; j < rounds; j += 4)
                        gload_lds16(src + j * 1024 + (lane << 4), dst + j * 1024);
                }
            }

            const unsigned short* RsB = (const unsigned short*)(RsBase + buf * 14336);
            const int nv = (vg < 7) ? 3 : 4;
            const int rowstride = (vg < 7) ? 84 : 112;

            // stage 1: X3 C-frags for the nv v's of this group (MFMA)
            f32x4 c[4];
            #pragma unroll
            for (int iv = 0; iv < 4; iv++) {
                if (iv >= nv) break;
                const int v   = vg * 3 + iv;
                const int row = ln15 * 25 + v;
                const int sw  = row & 7;
                bf16x8 a0 = *(const bf16x8*)&xb[row * 64 + ((q ^ sw) << 3)];
                bf16x8 a1 = *(const bf16x8*)&xb[row * 64 + (((4 + q) ^ sw) << 3)];
                f32x4 cc; cc[0] = bias; cc[1] = bias; cc[2] = bias; cc[3] = bias;
                cc = __builtin_amdgcn_mfma_f32_16x16x32_bf16(a0, bfr[0], cc, 0, 0, 0);
                cc = __builtin_amdgcn_mfma_f32_16x16x32_bf16(a1, bfr[1], cc, 0, 0, 0);
                c[iv] = cc;
            }
            // stage 2: y[u][t-pair] += R[og][v][u] * X3  (v_pk_fma_f32)
            #pragma unroll
            for (int iv = 0; iv < 4; iv++) {
                if (iv >= nv) break;
                const unsigned short* rr = &RsB[og * rowstride + iv * 28];
                f32x2 c01, c23;
                c01[0] = c[iv][0]; c01[1] = c[iv][1];
                c23[0] = c[iv][2]; c23[1] = c[iv][3];
                #pragma unroll
                for (int ug = 0; ug < 6; ug++) {
                    ushort4 r4 = *(const ushort4*)(rr + ug * 4);
                    float f0 = bf2f(r4.x), f1 = bf2f(r4.y);
                    float f2 = bf2f(r4.z), f3 = bf2f(r4.w);
                    yacc[ug * 4 + 0][0] += f0 * c01; yacc[ug * 4 + 0][1] += f0 * c23;
                    yacc[ug * 4 + 1][0] += f1 * c01; yacc[ug * 4 + 1][1] += f1 * c23;
                    yacc[ug * 4 + 2][0] += f2 * c01; yacc[ug * 4 + 2][1] += f2 * c23;
                    yacc[ug * 4 + 3][0] += f3 * c01; yacc[ug * 4 + 3][1] += f3 * c23;
                }
                float f24 = bf2f(rr[24]);
                yacc[24][0] += f24 * c01;
                yacc[24][1] += f24 * c23;
            }

            __syncthreads();   // drains prefetch DMA + all waves done with buf
            buf ^= 1;
        }
    }

    // ---- store y[n][og][t0 + q*4 + r][u] (scalar dwords, exact write-size) + BN ----
    float* op = out + (n * 64 + og) * 6400 + t0 * 25;
    float s1 = 0.f, s2 = 0.f;
    #pragma unroll
    for (int r = 0; r < 4; r++) {
        float* opr = op + (q * 4 + r) * 25;
        const int h = r >> 1, jj = r & 1;
        #pragma unroll
        for (int u = 0; u < 25; u++) {
            float vv = yacc[u][h][jj];
            opr[u] = vv;
            s1 += vv; s2 += vv * vv;
        }
    }
    s1 += __shfl_xor(s1, 16); s1 += __shfl_xor(s1, 32);
    s2 += __shfl_xor(s2, 16); s2 += __shfl_xor(s2, 32);
    if (q == 0) {
        atomicAdd(&bnacc[og * 16], s1);             // 64B-strided slots
        atomicAdd(&bnacc[1024 + og * 16], s2);
    }
}

// ---------------- K5: normalize + residual + relu (2 float4 / thread) ----------------
// 6,553,600 float4 -> 12800 blocks x 256 threads x 2
__global__ __launch_bounds__(256) void k_final(
    float* __restrict__ out, const float* __restrict__ x,
    const float* __restrict__ bnacc,
    const float* __restrict__ bnw, const float* __restrict__ bnb) {
    const int base = blockIdx.x * 512 + threadIdx.x;
    const float cnt = 1.f / 409600.f;
    #pragma unroll
    for (int e = 0; e < 2; e++) {
        const int idx4 = base + e * 256;
        const int o = (idx4 / 1600) & 63;
        float mean = bnacc[o * 16] * cnt;
        float var = bnacc[1024 + o * 16] * cnt - mean * mean;
        float inv = rsqrtf(var + 1e-5f);
        float sc = bnw[o] * inv;
        float sh = bnb[o] - mean * sc;
        float4 y = ((const float4*)out)[idx4];
        float4 xv = ((const float4*)x)[idx4];
        y.x = fmaxf(y.x * sc + sh + xv.x, 0.f);
        y.y = fmaxf(y.y * sc + sh + xv.y, 0.f);
        y.z = fmaxf(y.z * sc + sh + xv.z, 0.f);
        y.w = fmaxf(y.w * sc + sh + xv.w, 0.f);
        ((float4*)out)[idx4] = y;
    }
}

extern "C" void kernel_launch(void* const* d_in, const int* in_sizes, int n_in,
                              void* d_out, int out_size, void* d_ws, size_t ws_size,
                              hipStream_t stream) {
    const float* x     = (const float*)d_in[0];
    const float* A     = (const float*)d_in[1];
    const float* alpha = (const float*)d_in[2];
    const float* w1    = (const float*)d_in[3];
    const float* b1    = (const float*)d_in[4];
    const float* w2    = (const float*)d_in[5];
    const float* b2    = (const float*)d_in[6];
    const float* w3    = (const float*)d_in[7];
    const float* b3    = (const float*)d_in[8];
    const float* w4    = (const float*)d_in[9];
    const float* b4    = (const float*)d_in[10];
    const float* pw1   = (const float*)d_in[11];
    const float* pb1   = (const float*)d_in[12];
    const float* pw2   = (const float*)d_in[13];
    const float* pb2   = (const float*)d_in[14];
    const float* dww   = (const float*)d_in[15];
    const float* pjw   = (const float*)d_in[16];
    const float* beta  = (const float*)d_in[17];
    const float* gamma = (const float*)d_in[18];
    const float* bnw   = (const float*)d_in[19];
    const float* bnb   = (const float*)d_in[20];
    float* out = (float*)d_out;
    float* ws  = (float*)d_ws;
    unsigned short* wsR = (unsigned short*)((char*)d_ws + WS_R_BYTE);
    float* wsBN = (float*)((char*)d_ws + WS_BN_BYTE);

    k_xm<<<4096, 256, 0, stream>>>(x, ws, wsBN);
    k_small<<<192, 512, 0, stream>>>(ws, wsR, A, alpha, w1, b1, w2, b2,
                                     w4, b4, pw1, pb1, pw2, pb2, dww, pjw,
                                     beta, gamma);
    k_main<<<1024, 256, 0, stream>>>(x, w3, b3, wsR, out, wsBN);
    k_final<<<12800, 256, 0, stream>>>(out, x, wsBN, bnw, bnb);
}